// Round 8
// baseline (422.173 us; speedup 1.0000x reference)
//
#include <hip/hip_runtime.h>

// LSTM B=4096, T=512, I=2, H=50, O=3 — MFMA bf16x3, round 8.
// Changes vs round 7 (which was latency-bound at 1 wave/SIMD):
//  * 8 waves/block (512 thr), 256 blocks: wave pair (wv, half) duplicates the
//    24-MFMA accumulation (MFMA pipe was 21% busy -> duplication ~free) but
//    each wave runs the epilogue for only 2 of its 4 C-rows (r = 2*half+rr).
//    -> 2 waves/SIMD hide latency; per-wave trans chain halves.
//  * merged-rcp gates: sig(i)*tanh(g) = (eg-1)*rcp((1+ei)*(eg+1)), same for
//    sig(o)*tanh(c): 8 trans/cell instead of 10. c clamped to +-32 (inf guard).
// K-dim carries everything (k<50 h, k=50/51 x, k=52 bias*1.0); ONE barrier/t.

typedef short bf16x8 __attribute__((ext_vector_type(8)));
typedef float f32x4  __attribute__((ext_vector_type(4)));

#define T_STEPS 512
#define HID     50
#define ROWS    16
#define RSTRIDE 272                        // 17 x 16B granules per m-row
#define HBUF_SZ (ROWS * RSTRIDE)           // 4352 B
#define HF_OFF  (2 * HBUF_SZ)              // 8704 B
#define ARENA_SZ (HF_OFF + ROWS * 64 * 4)  // 12800 B
#define NTHREADS 512

#define L2E  1.442695040888963f            // log2(e)
#define L2E2 2.885390081777927f            // 2*log2(e)

// (hi bf16 in low short, lo bf16 in high short), round-to-nearest both
__device__ __forceinline__ unsigned pack_hilo(float f) {
    unsigned u  = __float_as_uint(f);
    unsigned hi = (u + 0x7fffu + ((u >> 16) & 1u)) >> 16;
    float    fh = __uint_as_float(hi << 16);
    float    rl = f - fh;
    unsigned ul = __float_as_uint(rl);
    unsigned lo = (ul + 0x7fffu + ((ul >> 16) & 1u)) >> 16;
    return (hi & 0xFFFFu) | (lo << 16);
}

__global__ __launch_bounds__(NTHREADS, 2) void lstm_mfma4_kernel(
    const float* __restrict__ x,     // [B,T,2]
    const float* __restrict__ W_ih,  // [200,2]
    const float* __restrict__ W_hh,  // [200,50]
    const float* __restrict__ b_ih,  // [200]
    const float* __restrict__ b_hh,  // [200]
    const float* __restrict__ W_fc,  // [3,50]
    const float* __restrict__ b_fc,  // [3]
    float* __restrict__ out)         // [B,3]
{
    __shared__ __align__(16) char arena[ARENA_SZ];

    const int tid  = threadIdx.x;
    const int lane = tid & 63;
    const int wvf  = tid >> 6;         // 0..7
    const int wv   = wvf >> 1;         // unit-block 0..3
    const int half = wvf & 1;          // row-half: epilogue rows r=2*half+rr
    const int col  = lane & 15;        // C col (unit) / A row (m) index
    const int grp  = lane >> 4;        // k-group / C row-group
    const int u    = wv * 16 + col;    // owned unit (0..63, 50 real)
    const int b0   = blockIdx.x * ROWS;

    // ---- zero arena ----
    for (int i = tid; i < ARENA_SZ / 4; i += NTHREADS) ((int*)arena)[i] = 0;

    // ---- B-frags in regs: k carries units + x-slots + bias-slot ----
    bf16x8 whi[4][2], wlo[4][2];
#pragma unroll
    for (int g = 0; g < 4; ++g) {
#pragma unroll
        for (int kt = 0; kt < 2; ++kt) {
            bf16x8 H, L;
#pragma unroll
            for (int e = 0; e < 8; ++e) {
                int k = kt * 32 + grp * 8 + e;
                float v = 0.f;
                if (u < HID) {
                    int j = g * HID + u;
                    if      (k < HID)  v = W_hh[j * HID + k];
                    else if (k == 50)  v = W_ih[2 * j + 0];
                    else if (k == 51)  v = W_ih[2 * j + 1];
                    else if (k == 52)  v = b_ih[j] + b_hh[j];
                }
                unsigned p = pack_hilo(v);
                H[e] = (short)(p & 0xFFFFu);
                L[e] = (short)(p >> 16);
            }
            whi[g][kt] = H;
            wlo[g][kt] = L;
        }
    }

    __syncthreads();   // zeroing complete

    // const-1.0 at k=52 (chunk 6, elems 4..5 b32: hi(k52)=0x3F80, hi(k53)=0),
    // both buffers; lo plane stays zero.
    if (tid < 2 * ROWS) {
        int buf = tid >> 4, m = tid & 15;
        *(unsigned*)(arena + buf * HBUF_SZ + m * RSTRIDE + 6 * 32 + 4 * 2) = 0x00003F80u;
    }
    // x writer lanes: wave 0, lanes 0..31 -> (m 0..15) x (component 0..1)
    const int  xm = lane & 15;
    const int  xw = (lane >> 4) & 1;
    const bool xwriter = (wvf == 0) && (lane < 32);
    const float* xptr = x + (size_t)(b0 + xm) * (T_STEPS * 2) + xw;
    if (xwriter) {   // x(t=0) into buffer 0: k=50+xw -> chunk 6, elem 2+xw
        unsigned p = pack_hilo(xptr[0]);
        char* cell = arena + xm * RSTRIDE + 6 * 32 + (2 + xw) * 2;
        *(short*)cell        = (short)(p & 0xFFFFu);
        *(short*)(cell + 16) = (short)(p >> 16);
    }
    float xpre = xwriter ? xptr[1 * 2] : 0.f;   // prefetch x(t=1)

    float c2[2]   = {0.f, 0.f};    // cell state for my 2 epilogue rows
    float hreg[2] = {0.f, 0.f};

    __syncthreads();

    int pb = 0;
    for (int t = 0; t < T_STEPS; ++t) {
        // ---- A-frags: 4 raw ds_read_b128 ----
        const char* hb = arena + pb * HBUF_SZ + col * RSTRIDE;
        bf16x8 ah[2], al[2];
#pragma unroll
        for (int kt = 0; kt < 2; ++kt) {
            const char* p = hb + (kt * 4 + grp) * 32;
            ah[kt] = *(const bf16x8*)p;
            al[kt] = *(const bf16x8*)(p + 16);
        }

        // ---- 4 gate tiles x (2 kt x 3 emulation terms) = 24 MFMA ----
        f32x4 acc[4];
#pragma unroll
        for (int g = 0; g < 4; ++g) {
            f32x4 a = {0.f, 0.f, 0.f, 0.f};
            a = __builtin_amdgcn_mfma_f32_16x16x32_bf16(ah[0], whi[g][0], a, 0, 0, 0);
            a = __builtin_amdgcn_mfma_f32_16x16x32_bf16(ah[1], whi[g][1], a, 0, 0, 0);
            a = __builtin_amdgcn_mfma_f32_16x16x32_bf16(al[0], whi[g][0], a, 0, 0, 0);
            a = __builtin_amdgcn_mfma_f32_16x16x32_bf16(al[1], whi[g][1], a, 0, 0, 0);
            a = __builtin_amdgcn_mfma_f32_16x16x32_bf16(ah[0], wlo[g][0], a, 0, 0, 0);
            a = __builtin_amdgcn_mfma_f32_16x16x32_bf16(ah[1], wlo[g][1], a, 0, 0, 0);
            acc[g] = a;
        }

        // ---- epilogue: only rows r = 2*half + rr (2 of 4 cells) ----
        char* db = arena + (pb ^ 1) * HBUF_SZ;
#pragma unroll
        for (int rr = 0; rr < 2; ++rr) {
            const int r = 2 * half + rr;
            float pi = acc[0][r], pf = acc[1][r], pg = acc[2][r], po = acc[3][r];
            float ei = __builtin_amdgcn_exp2f(-L2E  * pi);
            float ef = __builtin_amdgcn_exp2f(-L2E  * pf);
            float eg = __builtin_amdgcn_exp2f( L2E2 * pg);
            float eo = __builtin_amdgcn_exp2f(-L2E  * po);
            float sf    = __builtin_amdgcn_rcpf(1.0f + ef);
            float ig_tg = (eg - 1.0f) * __builtin_amdgcn_rcpf((1.0f + ei) * (eg + 1.0f));
            float c = sf * c2[rr] + ig_tg;
            c = fminf(fmaxf(c, -32.0f), 32.0f);      // keep exp2 finite
            c2[rr] = c;
            float ec = __builtin_amdgcn_exp2f(L2E2 * c);
            float h  = (ec - 1.0f) * __builtin_amdgcn_rcpf((1.0f + eo) * (ec + 1.0f));
            hreg[rr] = h;
            if (u < HID) {
                int m = grp * 4 + r;
                unsigned p = pack_hilo(h);
                char* cell = db + m * RSTRIDE + (u >> 3) * 32 + (u & 7) * 2;
                *(short*)cell        = (short)(p & 0xFFFFu);
                *(short*)(cell + 16) = (short)(p >> 16);
            }
        }

        // ---- x(t+1) into next buffer; prefetch x(t+2) ----
        if (xwriter) {
            unsigned p = pack_hilo(xpre);
            char* cell = db + xm * RSTRIDE + 6 * 32 + (2 + xw) * 2;
            *(short*)cell        = (short)(p & 0xFFFFu);
            *(short*)(cell + 16) = (short)(p >> 16);
            int t2 = (t + 2 < T_STEPS) ? t + 2 : T_STEPS - 1;
            xpre = xptr[(size_t)t2 * 2];
        }

        pb ^= 1;
        __syncthreads();
    }

    // ---- final FC: gather fp32 h, 48 threads compute out ----
    float* hf = (float*)(arena + HF_OFF);   // [16][64]
#pragma unroll
    for (int rr = 0; rr < 2; ++rr)
        hf[(grp * 4 + 2 * half + rr) * 64 + u] = hreg[rr];
    __syncthreads();
    if (tid < ROWS * 3) {
        int m = tid / 3, o = tid - m * 3;
        float s = b_fc[o];
        for (int k = 0; k < HID; ++k)
            s += hf[m * 64 + k] * W_fc[o * HID + k];
        out[(size_t)(b0 + m) * 3 + o] = s;
    }
}

extern "C" void kernel_launch(void* const* d_in, const int* in_sizes, int n_in,
                              void* d_out, int out_size, void* d_ws, size_t ws_size,
                              hipStream_t stream) {
    const float* x    = (const float*)d_in[0];
    const float* W_ih = (const float*)d_in[1];
    const float* W_hh = (const float*)d_in[2];
    const float* b_ih = (const float*)d_in[3];
    const float* b_hh = (const float*)d_in[4];
    const float* W_fc = (const float*)d_in[5];
    const float* b_fc = (const float*)d_in[6];
    float* out = (float*)d_out;

    dim3 grid(4096 / ROWS);   // 256 blocks -> 1 per CU
    dim3 block(NTHREADS);     // 8 waves -> 2 per SIMD
    lstm_mfma4_kernel<<<grid, block, 0, stream>>>(x, W_ih, W_hh, b_ih, b_hh,
                                                  W_fc, b_fc, out);
}

// Round 9
// 311.981 us; speedup vs baseline: 1.3532x; 1.3532x over previous
//
#include <hip/hip_runtime.h>

// LSTM B=4096, T=512, I=2, H=50, O=3 — MFMA bf16x3, round 9.
// KEY CHANGE vs r7/r8: operands swapped, D = W*H.
//   A (M dim) = weight rows, m = 4*u_local + gate  (VGPR-resident frags)
//   B (N dim) = h, n = batch row                   (LDS ds_read_b128)
//   C: col=lane&15=batch, grp=(lane>>4)=unit-in-tile, reg=GATE
// -> each lane holds all 4 gates of ONE cell in its 4 acc regs: the N axis
// (gates x units, 13 real 16-wide tiles) splits across 8 waves with NO
// duplicated MFMA, no transpose, no extra barrier. Wave 7 (pad tiles) is the
// x-writer. Merged-rcp gates (8 trans/cell). ONE barrier per t.
// K-dim carries everything: k<50 h, k=50/51 x0/x1, k=52 bias (const 1.0).

typedef short bf16x8 __attribute__((ext_vector_type(8)));
typedef float f32x4  __attribute__((ext_vector_type(4)));

#define T_STEPS 512
#define HID     50
#define ROWS    16
#define RSTRIDE 272                        // 17 x 16B granules per m-row
#define HBUF_SZ (ROWS * RSTRIDE)           // 4352 B
#define HF_OFF  (2 * HBUF_SZ)              // 8704 B
#define ARENA_SZ (HF_OFF + ROWS * 64 * 4)  // 12800 B
#define NTHREADS 512

#define L2E  1.442695040888963f            // log2(e)
#define L2E2 2.885390081777927f            // 2*log2(e)

// (hi bf16 in low short, lo bf16 in high short), round-to-nearest both
__device__ __forceinline__ unsigned pack_hilo(float f) {
    unsigned u  = __float_as_uint(f);
    unsigned hi = (u + 0x7fffu + ((u >> 16) & 1u)) >> 16;
    float    fh = __uint_as_float(hi << 16);
    float    rl = f - fh;
    unsigned ul = __float_as_uint(rl);
    unsigned lo = (ul + 0x7fffu + ((ul >> 16) & 1u)) >> 16;
    return (hi & 0xFFFFu) | (lo << 16);
}

__global__ __launch_bounds__(NTHREADS, 2) void lstm_mfma5_kernel(
    const float* __restrict__ x,     // [B,T,2]
    const float* __restrict__ W_ih,  // [200,2]
    const float* __restrict__ W_hh,  // [200,50]
    const float* __restrict__ b_ih,  // [200]
    const float* __restrict__ b_hh,  // [200]
    const float* __restrict__ W_fc,  // [3,50]
    const float* __restrict__ b_fc,  // [3]
    float* __restrict__ out)         // [B,3]
{
    __shared__ __align__(16) char arena[ARENA_SZ];

    const int tid  = threadIdx.x;
    const int lane = tid & 63;
    const int wvf  = tid >> 6;         // wave 0..7
    const int col  = lane & 15;        // C col = batch row; A row index m
    const int grp  = lane >> 4;        // k-group; C row-group = unit-in-tile
    const int b0   = blockIdx.x * ROWS;

    // ---- zero arena ----
    for (int i = tid; i < ARENA_SZ / 4; i += NTHREADS) ((int*)arena)[i] = 0;

    // ---- A-frags (weights) in regs: tiles tau = 2*wvf + tt ----
    // A[m][k], lane provides m = col: unit u = tau*4 + (m>>2), gate g = m&3.
    bf16x8 awhi[2][2], awlo[2][2];   // [tt][kt]
    bool act[2];
#pragma unroll
    for (int tt = 0; tt < 2; ++tt) {
        const int tau = wvf * 2 + tt;
        act[tt] = (tau * 4) < HID;
        const int u = tau * 4 + (col >> 2);
        const int g = col & 3;
#pragma unroll
        for (int kt = 0; kt < 2; ++kt) {
            bf16x8 H, L;
#pragma unroll
            for (int e = 0; e < 8; ++e) {
                int k = kt * 32 + grp * 8 + e;
                float v = 0.f;
                if (u < HID) {
                    int j = g * HID + u;
                    if      (k < HID)  v = W_hh[j * HID + k];
                    else if (k == 50)  v = W_ih[2 * j + 0];
                    else if (k == 51)  v = W_ih[2 * j + 1];
                    else if (k == 52)  v = b_ih[j] + b_hh[j];
                }
                unsigned p = pack_hilo(v);
                H[e] = (short)(p & 0xFFFFu);
                L[e] = (short)(p >> 16);
            }
            awhi[tt][kt] = H;
            awlo[tt][kt] = L;
        }
    }

    __syncthreads();   // zeroing complete

    // const-1.0 at k=52 (chunk 6, elems 4..5 b32: hi(k52)=0x3F80, hi(k53)=0),
    // both buffers; lo plane stays zero.
    if (tid < 2 * ROWS) {
        int buf = tid >> 4, m = tid & 15;
        *(unsigned*)(arena + buf * HBUF_SZ + m * RSTRIDE + 6 * 32 + 4 * 2) = 0x00003F80u;
    }
    // x writer: wave 7 (its tiles are all pad), lanes 0..31 -> (m, comp)
    const int  xm = lane & 15;
    const int  xw = (lane >> 4) & 1;
    const bool xwriter = (wvf == 7) && (lane < 32);
    const float* xptr = x + (size_t)(b0 + xm) * (T_STEPS * 2) + xw;
    if (xwriter) {   // x(t=0) into buffer 0: k=50+xw -> chunk 6, elem 2+xw
        unsigned p = pack_hilo(xptr[0]);
        char* cell = arena + xm * RSTRIDE + 6 * 32 + (2 + xw) * 2;
        *(short*)cell        = (short)(p & 0xFFFFu);
        *(short*)(cell + 16) = (short)(p >> 16);
    }
    float xpre = xwriter ? xptr[1 * 2] : 0.f;   // prefetch x(t=1)

    float c2[2]   = {0.f, 0.f};    // cell state: my cell per tile
    float hreg[2] = {0.f, 0.f};

    __syncthreads();

    int pb = 0;
    for (int t = 0; t < T_STEPS; ++t) {
        // ---- B-frags (h/x/1.0): 4 raw ds_read_b128, col = batch row ----
        const char* hb = arena + pb * HBUF_SZ + col * RSTRIDE;
        bf16x8 bh[2], bl[2];
#pragma unroll
        for (int kt = 0; kt < 2; ++kt) {
            const char* p = hb + (kt * 4 + grp) * 32;
            bh[kt] = *(const bf16x8*)p;
            bl[kt] = *(const bf16x8*)(p + 16);
        }

        // ---- per active tile: 6 MFMA; C regs = the 4 gates of my cell ----
        f32x4 acc[2];
#pragma unroll
        for (int tt = 0; tt < 2; ++tt) {
            if (!act[tt]) continue;
            f32x4 a = {0.f, 0.f, 0.f, 0.f};
            a = __builtin_amdgcn_mfma_f32_16x16x32_bf16(awhi[tt][0], bh[0], a, 0, 0, 0);
            a = __builtin_amdgcn_mfma_f32_16x16x32_bf16(awhi[tt][1], bh[1], a, 0, 0, 0);
            a = __builtin_amdgcn_mfma_f32_16x16x32_bf16(awlo[tt][0], bh[0], a, 0, 0, 0);
            a = __builtin_amdgcn_mfma_f32_16x16x32_bf16(awlo[tt][1], bh[1], a, 0, 0, 0);
            a = __builtin_amdgcn_mfma_f32_16x16x32_bf16(awhi[tt][0], bl[0], a, 0, 0, 0);
            a = __builtin_amdgcn_mfma_f32_16x16x32_bf16(awhi[tt][1], bl[1], a, 0, 0, 0);
            acc[tt] = a;
        }

        // ---- epilogue: 1 cell per lane per active tile ----
        char* db = arena + (pb ^ 1) * HBUF_SZ;
#pragma unroll
        for (int tt = 0; tt < 2; ++tt) {
            if (!act[tt]) continue;
            const int u = (wvf * 2 + tt) * 4 + grp;   // my unit
            float pi = acc[tt][0], pf = acc[tt][1];
            float pg = acc[tt][2], po = acc[tt][3];
            float ei = __builtin_amdgcn_exp2f(-L2E  * pi);
            float ef = __builtin_amdgcn_exp2f(-L2E  * pf);
            float eg = __builtin_amdgcn_exp2f( L2E2 * pg);
            float eo = __builtin_amdgcn_exp2f(-L2E  * po);
            float sf    = __builtin_amdgcn_rcpf(1.0f + ef);
            float ig_tg = (eg - 1.0f) * __builtin_amdgcn_rcpf((1.0f + ei) * (eg + 1.0f));
            float c = sf * c2[tt] + ig_tg;
            c = fminf(fmaxf(c, -32.0f), 32.0f);       // keep exp2 finite
            c2[tt] = c;
            float ec = __builtin_amdgcn_exp2f(L2E2 * c);
            float h  = (ec - 1.0f) * __builtin_amdgcn_rcpf((1.0f + eo) * (ec + 1.0f));
            hreg[tt] = h;
            if (u < HID) {                            // skip pad units
                unsigned p = pack_hilo(h);
                char* cell = db + col * RSTRIDE + (u >> 3) * 32 + (u & 7) * 2;
                *(short*)cell        = (short)(p & 0xFFFFu);
                *(short*)(cell + 16) = (short)(p >> 16);
            }
        }

        // ---- x(t+1) into next buffer; prefetch x(t+2) ----
        if (xwriter) {
            unsigned p = pack_hilo(xpre);
            char* cell = db + xm * RSTRIDE + 6 * 32 + (2 + xw) * 2;
            *(short*)cell        = (short)(p & 0xFFFFu);
            *(short*)(cell + 16) = (short)(p >> 16);
            int t2 = (t + 2 < T_STEPS) ? t + 2 : T_STEPS - 1;
            xpre = xptr[(size_t)t2 * 2];
        }

        pb ^= 1;
        __syncthreads();
    }

    // ---- final FC: gather fp32 h, 48 threads compute out ----
    float* hf = (float*)(arena + HF_OFF);   // [16][64]
#pragma unroll
    for (int tt = 0; tt < 2; ++tt) {
        if (!act[tt]) continue;
        const int u = (wvf * 2 + tt) * 4 + grp;
        if (u < HID) hf[col * 64 + u] = hreg[tt];
    }
    __syncthreads();
    if (tid < ROWS * 3) {
        int m = tid / 3, o = tid - m * 3;
        float s = b_fc[o];
        for (int k = 0; k < HID; ++k)
            s += hf[m * 64 + k] * W_fc[o * HID + k];
        out[(size_t)(b0 + m) * 3 + o] = s;
    }
}

extern "C" void kernel_launch(void* const* d_in, const int* in_sizes, int n_in,
                              void* d_out, int out_size, void* d_ws, size_t ws_size,
                              hipStream_t stream) {
    const float* x    = (const float*)d_in[0];
    const float* W_ih = (const float*)d_in[1];
    const float* W_hh = (const float*)d_in[2];
    const float* b_ih = (const float*)d_in[3];
    const float* b_hh = (const float*)d_in[4];
    const float* W_fc = (const float*)d_in[5];
    const float* b_fc = (const float*)d_in[6];
    float* out = (float*)d_out;

    dim3 grid(4096 / ROWS);   // 256 blocks -> 1 per CU
    dim3 block(NTHREADS);     // 8 waves -> 2 per SIMD
    lstm_mfma5_kernel<<<grid, block, 0, stream>>>(x, W_ih, W_hh, b_ih, b_hh,
                                                  W_fc, b_fc, out);
}

// Round 10
// 308.387 us; speedup vs baseline: 1.3690x; 1.0117x over previous
//
#include <hip/hip_runtime.h>

// LSTM B=4096, T=512, I=2, H=50, O=3 — MFMA bf16x3, round 10.
// vs r9: same D = W*H decomposition, but 16 waves x 1 tile (1024 thr),
// 256 blocks -> 1 block/CU, 4 waves/SIMD. Per-CU issued work UNCHANGED
// (78 MFMA/t, 1 cell/lane epilogue); per-wave work halves and 4 waves/SIMD
// hide ds_read/MFMA/trans latency. Accumulator chain split 2x3.
//   A (M) = weight rows, m = 4*u_local + gate  (VGPR frags, tile tau = wave)
//   B (N) = h, n = batch row                   (4x ds_read_b128, broadcast)
//   C: col=lane&15=batch, grp=lane>>4=unit-in-tile, reg=GATE
// K carries everything: k<50 h, k=50/51 x0/x1, k=52 bias (const 1.0).
// Waves 0..12 active, wave 13 = x-writer, 14/15 barrier-only. ONE barrier/t.

typedef short bf16x8 __attribute__((ext_vector_type(8)));
typedef float f32x4  __attribute__((ext_vector_type(4)));

#define T_STEPS 512
#define HID     50
#define ROWS    16
#define RSTRIDE 272                        // 17 x 16B granules per m-row
#define HBUF_SZ (ROWS * RSTRIDE)           // 4352 B
#define HF_OFF  (2 * HBUF_SZ)              // 8704 B
#define ARENA_SZ (HF_OFF + ROWS * 64 * 4)  // 12800 B
#define NTHREADS 1024

#define L2E  1.442695040888963f            // log2(e)
#define L2E2 2.885390081777927f            // 2*log2(e)

// (hi bf16 in low short, lo bf16 in high short), round-to-nearest both
__device__ __forceinline__ unsigned pack_hilo(float f) {
    unsigned u  = __float_as_uint(f);
    unsigned hi = (u + 0x7fffu + ((u >> 16) & 1u)) >> 16;
    float    fh = __uint_as_float(hi << 16);
    float    rl = f - fh;
    unsigned ul = __float_as_uint(rl);
    unsigned lo = (ul + 0x7fffu + ((ul >> 16) & 1u)) >> 16;
    return (hi & 0xFFFFu) | (lo << 16);
}

__global__ __launch_bounds__(NTHREADS, 4) void lstm_mfma6_kernel(
    const float* __restrict__ x,     // [B,T,2]
    const float* __restrict__ W_ih,  // [200,2]
    const float* __restrict__ W_hh,  // [200,50]
    const float* __restrict__ b_ih,  // [200]
    const float* __restrict__ b_hh,  // [200]
    const float* __restrict__ W_fc,  // [3,50]
    const float* __restrict__ b_fc,  // [3]
    float* __restrict__ out)         // [B,3]
{
    __shared__ __align__(16) char arena[ARENA_SZ];

    const int tid  = threadIdx.x;
    const int lane = tid & 63;
    const int tau  = tid >> 6;         // wave id == tile id 0..15
    const int col  = lane & 15;        // C col = batch row; A row index m
    const int grp  = lane >> 4;        // k-group; C row-group = unit-in-tile
    const int b0   = blockIdx.x * ROWS;
    const bool act = (tau * 4) < HID;  // waves 0..12 own a real tile

    // ---- zero arena ----
    for (int i = tid; i < ARENA_SZ / 4; i += NTHREADS) ((int*)arena)[i] = 0;

    // ---- A-frag (weights) in regs for my tile ----
    // A[m][k], lane provides m = col: unit u = tau*4 + (m>>2), gate g = m&3.
    bf16x8 awhi[2], awlo[2];   // [kt]
    if (act) {
        const int u = tau * 4 + (col >> 2);
        const int g = col & 3;
#pragma unroll
        for (int kt = 0; kt < 2; ++kt) {
            bf16x8 H, L;
#pragma unroll
            for (int e = 0; e < 8; ++e) {
                int k = kt * 32 + grp * 8 + e;
                float v = 0.f;
                if (u < HID) {
                    int j = g * HID + u;
                    if      (k < HID)  v = W_hh[j * HID + k];
                    else if (k == 50)  v = W_ih[2 * j + 0];
                    else if (k == 51)  v = W_ih[2 * j + 1];
                    else if (k == 52)  v = b_ih[j] + b_hh[j];
                }
                unsigned p = pack_hilo(v);
                H[e] = (short)(p & 0xFFFFu);
                L[e] = (short)(p >> 16);
            }
            awhi[kt] = H;
            awlo[kt] = L;
        }
    }

    __syncthreads();   // zeroing complete

    // const-1.0 at k=52 (chunk 6, elems 4..5 b32: hi(k52)=0x3F80, hi(k53)=0),
    // both buffers; lo plane stays zero.
    if (tid < 2 * ROWS) {
        int buf = tid >> 4, m = tid & 15;
        *(unsigned*)(arena + buf * HBUF_SZ + m * RSTRIDE + 6 * 32 + 4 * 2) = 0x00003F80u;
    }
    // x writer: wave 13 (pad tile), lanes 0..31 -> (m 0..15) x (comp 0..1)
    const int  xm = lane & 15;
    const int  xw = (lane >> 4) & 1;
    const bool xwriter = (tau == 13) && (lane < 32);
    const float* xptr = x + (size_t)(b0 + xm) * (T_STEPS * 2) + xw;
    if (xwriter) {   // x(t=0) into buffer 0: k=50+xw -> chunk 6, elem 2+xw
        unsigned p = pack_hilo(xptr[0]);
        char* cell = arena + xm * RSTRIDE + 6 * 32 + (2 + xw) * 2;
        *(short*)cell        = (short)(p & 0xFFFFu);
        *(short*)(cell + 16) = (short)(p >> 16);
    }
    float xpre = xwriter ? xptr[1 * 2] : 0.f;   // prefetch x(t=1)

    float creg = 0.f;    // cell state for my one cell
    float hreg = 0.f;

    __syncthreads();

    int pb = 0;
    for (int t = 0; t < T_STEPS; ++t) {
        char* db = arena + (pb ^ 1) * HBUF_SZ;

        if (act) {
            // ---- B-frags (h/x/1.0): 4 raw ds_read_b128, col = batch ----
            const char* hb = arena + pb * HBUF_SZ + col * RSTRIDE;
            bf16x8 bh[2], bl[2];
#pragma unroll
            for (int kt = 0; kt < 2; ++kt) {
                const char* p = hb + (kt * 4 + grp) * 32;
                bh[kt] = *(const bf16x8*)p;
                bl[kt] = *(const bf16x8*)(p + 16);
            }

            // ---- 6 MFMA, two independent 3-chains ----
            f32x4 a0 = {0.f, 0.f, 0.f, 0.f};
            f32x4 a1 = {0.f, 0.f, 0.f, 0.f};
            a0 = __builtin_amdgcn_mfma_f32_16x16x32_bf16(awhi[0], bh[0], a0, 0, 0, 0);
            a1 = __builtin_amdgcn_mfma_f32_16x16x32_bf16(awhi[1], bh[1], a1, 0, 0, 0);
            a0 = __builtin_amdgcn_mfma_f32_16x16x32_bf16(awlo[0], bh[0], a0, 0, 0, 0);
            a1 = __builtin_amdgcn_mfma_f32_16x16x32_bf16(awlo[1], bh[1], a1, 0, 0, 0);
            a0 = __builtin_amdgcn_mfma_f32_16x16x32_bf16(awhi[0], bl[0], a0, 0, 0, 0);
            a1 = __builtin_amdgcn_mfma_f32_16x16x32_bf16(awhi[1], bl[1], a1, 0, 0, 0);
            f32x4 acc = a0 + a1;

            // ---- epilogue: ONE cell (batch=col, unit=tau*4+grp) ----
            const int u = tau * 4 + grp;
            float pi = acc[0], pf = acc[1], pg = acc[2], po = acc[3];
            float ei = __builtin_amdgcn_exp2f(-L2E  * pi);
            float ef = __builtin_amdgcn_exp2f(-L2E  * pf);
            float eg = __builtin_amdgcn_exp2f( L2E2 * pg);
            float eo = __builtin_amdgcn_exp2f(-L2E  * po);
            float sf    = __builtin_amdgcn_rcpf(1.0f + ef);
            float ig_tg = (eg - 1.0f) * __builtin_amdgcn_rcpf((1.0f + ei) * (eg + 1.0f));
            float c = sf * creg + ig_tg;
            c = fminf(fmaxf(c, -32.0f), 32.0f);       // keep exp2 finite
            creg = c;
            float ec = __builtin_amdgcn_exp2f(L2E2 * c);
            float h  = (ec - 1.0f) * __builtin_amdgcn_rcpf((1.0f + eo) * (ec + 1.0f));
            hreg = h;
            if (u < HID) {                            // skip pad units
                unsigned p = pack_hilo(h);
                char* cell = db + col * RSTRIDE + (u >> 3) * 32 + (u & 7) * 2;
                *(short*)cell        = (short)(p & 0xFFFFu);
                *(short*)(cell + 16) = (short)(p >> 16);
            }
        }

        // ---- x(t+1) into next buffer; prefetch x(t+2) ----
        if (xwriter) {
            unsigned p = pack_hilo(xpre);
            char* cell = db + xm * RSTRIDE + 6 * 32 + (2 + xw) * 2;
            *(short*)cell        = (short)(p & 0xFFFFu);
            *(short*)(cell + 16) = (short)(p >> 16);
            int t2 = (t + 2 < T_STEPS) ? t + 2 : T_STEPS - 1;
            xpre = xptr[(size_t)t2 * 2];
        }

        pb ^= 1;
        __syncthreads();
    }

    // ---- final FC: gather fp32 h, 48 threads compute out ----
    float* hf = (float*)(arena + HF_OFF);   // [16][64]
    if (act) {
        const int u = tau * 4 + grp;
        if (u < HID) hf[col * 64 + u] = hreg;
    }
    __syncthreads();
    if (tid < ROWS * 3) {
        int m = tid / 3, o = tid - m * 3;
        float s = b_fc[o];
        for (int k = 0; k < HID; ++k)
            s += hf[m * 64 + k] * W_fc[o * HID + k];
        out[(size_t)(b0 + m) * 3 + o] = s;
    }
}

extern "C" void kernel_launch(void* const* d_in, const int* in_sizes, int n_in,
                              void* d_out, int out_size, void* d_ws, size_t ws_size,
                              hipStream_t stream) {
    const float* x    = (const float*)d_in[0];
    const float* W_ih = (const float*)d_in[1];
    const float* W_hh = (const float*)d_in[2];
    const float* b_ih = (const float*)d_in[3];
    const float* b_hh = (const float*)d_in[4];
    const float* W_fc = (const float*)d_in[5];
    const float* b_fc = (const float*)d_in[6];
    float* out = (float*)d_out;

    dim3 grid(4096 / ROWS);   // 256 blocks -> 1 per CU
    dim3 block(NTHREADS);     // 16 waves -> 4 per SIMD
    lstm_mfma6_kernel<<<grid, block, 0, stream>>>(x, W_ih, W_hh, b_ih, b_hh,
                                                  W_fc, b_fc, out);
}